// Round 1
// baseline (1042.376 us; speedup 1.0000x reference)
//
#include <hip/hip_runtime.h>
#include <math.h>

#define SCALEF 0.25f   // 1/sqrt(D=16)

// ======================= CSR build =======================
__global__ void k_hist(const int* __restrict__ dst, int* __restrict__ counts, int E) {
  int i = blockIdx.x * 256 + threadIdx.x;
  if (i < E) atomicAdd(&counts[dst[i]], 1);
}

__global__ __launch_bounds__(1024) void k_scan1(const int* __restrict__ counts,
                                                int* __restrict__ excl,
                                                int* __restrict__ bsums, int n) {
  __shared__ int sd[1024];
  int t = threadIdx.x;
  int i = blockIdx.x * 1024 + t;
  int v = (i < n) ? counts[i] : 0;
  sd[t] = v;
  __syncthreads();
  for (int off = 1; off < 1024; off <<= 1) {
    int x = (t >= off) ? sd[t - off] : 0;
    __syncthreads();
    sd[t] += x;
    __syncthreads();
  }
  if (i < n) excl[i] = sd[t] - v;
  if (t == 1023) bsums[blockIdx.x] = sd[1023];
}

__global__ void k_scan2(int* bsums, int nb) {
  if (threadIdx.x == 0 && blockIdx.x == 0) {
    int run = 0;
    for (int i = 0; i < nb; ++i) { int v = bsums[i]; bsums[i] = run; run += v; }
  }
}

__global__ __launch_bounds__(1024) void k_scan3(int* __restrict__ rowptr, int* __restrict__ cursor,
                                                const int* __restrict__ bsums, int n, int Etot) {
  int i = blockIdx.x * 1024 + threadIdx.x;
  if (i < n) { int v = rowptr[i] + bsums[blockIdx.x]; rowptr[i] = v; cursor[i] = v; }
  if (i == 0) rowptr[n] = Etot;
}

__global__ void k_scatter(const int* __restrict__ dst, int* __restrict__ cursor,
                          int* __restrict__ colidx, int E) {
  int i = blockIdx.x * 256 + threadIdx.x;
  if (i < E) { int pos = atomicAdd(&cursor[dst[i]], 1); colidx[pos] = i; }
}

// ======================= node linear: Q,K,V,Skip =======================
// block = 256 threads, handles 32 nodes; stages 2 of the 4 weight mats per phase.
#define LNODES 32
__global__ __launch_bounds__(256) void k_lin(const float* __restrict__ X,
    const float* __restrict__ Wq, const float* __restrict__ bq,
    const float* __restrict__ Wk, const float* __restrict__ bk,
    const float* __restrict__ Wv, const float* __restrict__ bv,
    const float* __restrict__ Ws, const float* __restrict__ bs,
    float* __restrict__ Q, float* __restrict__ K, float* __restrict__ V, float* __restrict__ S,
    int n) {
  __shared__ float Wl[2][64][64];    // 32 KiB
  __shared__ float Xl[LNODES][64];   // 8 KiB
  const int t = threadIdx.x;
  const int n0 = blockIdx.x * LNODES;

  for (int i = t; i < LNODES * 64; i += 256) {
    int node = n0 + (i >> 6);
    Xl[i >> 6][i & 63] = (node < n) ? X[node * 64 + (i & 63)] : 0.f;
  }

  const float* Wm[4] = {Wq, Wk, Wv, Ws};
  const float* bm[4] = {bq, bk, bv, bs};
  float* Om[4] = {Q, K, V, S};

  const int c    = t & 63;        // output column
  const int g    = t >> 6;        // wave id 0..3
  const int mloc = g & 1;         // which staged matrix
  const int half = g >> 1;        // which half of the node tile

  for (int ph = 0; ph < 2; ++ph) {
    __syncthreads();
    for (int i = t; i < 2 * 64 * 64; i += 256) {
      int mm = i >> 12;
      Wl[mm][(i >> 6) & 63][i & 63] = Wm[ph * 2 + mm][i & 4095];
    }
    __syncthreads();
    const int mat = ph * 2 + mloc;
    const float bias = bm[mat][c];
    float* O = Om[mat];
    for (int i = 0; i < LNODES / 2; ++i) {
      int nl = half * (LNODES / 2) + i;
      int node = n0 + nl;
      if (node >= n) break;
      float acc = bias;
      #pragma unroll
      for (int k = 0; k < 64; ++k) acc += Xl[nl][k] * Wl[mloc][k][c];
      O[node * 64 + c] = acc;
    }
  }
}

// ======================= fused edge/attention kernel =======================
// One wave (64 lanes) per destination node. Online softmax over incoming edges,
// edge projection e = edge_attr @ We computed in-register, beta-gate + ReLU fused.
__global__ __launch_bounds__(256) void k_attn(
    const float* __restrict__ Q, const float* __restrict__ K, const float* __restrict__ V,
    const float* __restrict__ S, const float* __restrict__ EA,
    const int* __restrict__ esrc, const int* __restrict__ colidx,
    const int* __restrict__ rowptr,
    const float* __restrict__ We, const float* __restrict__ Wb,
    float* __restrict__ Hout, int n) {
  __shared__ float WeL[16][64];   // 4 KiB
  __shared__ float WbL[192];
  const int t = threadIdx.x;
  for (int i = t; i < 16 * 64; i += 256) WeL[i >> 6][i & 63] = We[i];
  for (int i = t; i < 192; i += 256) WbL[i] = Wb[i];
  __syncthreads();

  const int lane = t & 63;
  const int w = t >> 6;
  const int node = blockIdx.x * 4 + w;
  if (node >= n) return;

  float qv = Q[node * 64 + lane] * SCALEF;
  float m = -1e30f, ssum = 0.f, acc = 0.f;
  const int r0 = rowptr[node], r1 = rowptr[node + 1];
  for (int r = r0; r < r1; ++r) {
    const int eid = colidx[r];
    const int sn = esrc[eid];
    const float* ea = EA + (size_t)eid * 16;
    float e = 0.f;
    #pragma unroll
    for (int j = 0; j < 16; ++j) e += ea[j] * WeL[j][lane];
    const float ke = K[sn * 64 + lane] + e;
    const float ve = V[sn * 64 + lane] + e;
    float prod = qv * ke;
    #pragma unroll
    for (int off = 1; off < 16; off <<= 1) prod += __shfl_xor(prod, off, 64);
    const float l = prod;                     // logit for this head
    const float mn = fmaxf(m, l);
    const float fold = expf(m - mn);
    const float p = expf(l - mn);
    ssum = ssum * fold + p;
    acc  = acc  * fold + p * ve;
    m = mn;
  }
  const float a  = acc / (ssum + 1e-16f);
  const float sk = S[node * 64 + lane];
  float contrib = a * WbL[lane] + sk * WbL[64 + lane] + (a - sk) * WbL[128 + lane];
  #pragma unroll
  for (int off = 1; off < 64; off <<= 1) contrib += __shfl_xor(contrib, off, 64);
  const float beta = 1.f / (1.f + expf(-contrib));
  float o = beta * sk + (1.f - beta) * a;
  Hout[node * 64 + lane] = fmaxf(o, 0.f);
}

// ======================= pooling (batch is sorted) =======================
#define PCHUNK 512
__global__ __launch_bounds__(64) void k_pool(const float* __restrict__ Hf, const int* __restrict__ batch,
    unsigned int* __restrict__ gmaxb, float* __restrict__ gsum, float* __restrict__ gcnt, int n) {
  const int lane = threadIdx.x;
  const int c0 = blockIdx.x * PCHUNK;
  if (c0 >= n) return;
  const int c1 = min(c0 + PCHUNK, n);
  int curg = batch[c0];
  float vmax = 0.f, vsum = 0.f, cnt = 0.f;
  for (int node = c0; node < c1; ++node) {
    const int g = batch[node];
    if (g != curg) {
      atomicMax(&gmaxb[curg * 64 + lane], __float_as_uint(vmax));
      atomicAdd(&gsum[curg * 64 + lane], vsum);
      if (lane == 0) atomicAdd(&gcnt[curg], cnt);
      curg = g; vmax = 0.f; vsum = 0.f; cnt = 0.f;
    }
    const float v = Hf[node * 64 + lane];
    vmax = fmaxf(vmax, v); vsum += v; cnt += 1.f;
  }
  atomicMax(&gmaxb[curg * 64 + lane], __float_as_uint(vmax));
  atomicAdd(&gsum[curg * 64 + lane], vsum);
  if (lane == 0) atomicAdd(&gcnt[curg], cnt);
}

// ======================= final MLP =======================
__global__ __launch_bounds__(256) void k_mlp(const unsigned int* __restrict__ gmaxb,
    const float* __restrict__ gsum, const float* __restrict__ gcnt,
    const float* __restrict__ Wlin, const float* __restrict__ blin,
    const float* __restrict__ Wout, const float* __restrict__ bout,
    float* __restrict__ out, int G) {
  __shared__ float cat[128];
  __shared__ float red[4];
  const int g = blockIdx.x;
  const int t = threadIdx.x;
  if (t < 64) cat[t] = __uint_as_float(gmaxb[g * 64 + t]);
  else if (t < 128) {
    const float c = gcnt[g];
    cat[t] = gsum[g * 64 + (t - 64)] / fmaxf(c, 1.f);
  }
  __syncthreads();
  float acc = blin[t];
  for (int j = 0; j < 128; ++j) acc += cat[j] * Wlin[j * 256 + t];
  float p = acc * Wout[t];
  #pragma unroll
  for (int off = 1; off < 64; off <<= 1) p += __shfl_xor(p, off, 64);
  if ((t & 63) == 0) red[t >> 6] = p;
  __syncthreads();
  if (t == 0) {
    const float z = red[0] + red[1] + red[2] + red[3] + bout[0];
    out[g] = 1.f / (1.f + expf(-z));
  }
}

// ======================= launcher =======================
extern "C" void kernel_launch(void* const* d_in, const int* in_sizes, int n_in,
                              void* d_out, int out_size, void* d_ws, size_t ws_size,
                              hipStream_t stream) {
  const float* x     = (const float*)d_in[0];
  const float* ea    = (const float*)d_in[1];
  const int*   eidx  = (const int*)d_in[2];
  const int*   batch = (const int*)d_in[3];
  const float *Wq0 = (const float*)d_in[4],  *bq0 = (const float*)d_in[5];
  const float *Wk0 = (const float*)d_in[6],  *bk0 = (const float*)d_in[7];
  const float *Wv0 = (const float*)d_in[8],  *bv0 = (const float*)d_in[9];
  const float *We0 = (const float*)d_in[10];
  const float *Ws0 = (const float*)d_in[11], *bs0 = (const float*)d_in[12];
  const float *Wb0 = (const float*)d_in[13];
  const float *Wq  = (const float*)d_in[14], *bq  = (const float*)d_in[15];
  const float *Wk  = (const float*)d_in[16], *bk  = (const float*)d_in[17];
  const float *Wv  = (const float*)d_in[18], *bv  = (const float*)d_in[19];
  const float *We  = (const float*)d_in[20];
  const float *Ws  = (const float*)d_in[21], *bs  = (const float*)d_in[22];
  const float *Wb  = (const float*)d_in[23];
  const float *Wlin = (const float*)d_in[24], *blin = (const float*)d_in[25];
  const float *Wout = (const float*)d_in[26], *bout = (const float*)d_in[27];

  const int N = in_sizes[0] / 64;
  const int E = in_sizes[2] / 2;
  const int G = out_size;          // 128 graphs, one sigmoid output each
  const int* esrc = eidx;
  const int* edst = eidx + E;

  // ---- workspace carve ----
  char* w = (char*)d_ws;
  auto alloc = [&](size_t bytes) -> void* {
    void* p = (void*)w;
    w += (bytes + 255) & ~(size_t)255;
    return p;
  };
  float* Qb = (float*)alloc((size_t)N * 64 * 4);
  float* Kb = (float*)alloc((size_t)N * 64 * 4);
  float* Vb = (float*)alloc((size_t)N * 64 * 4);
  float* Sb = (float*)alloc((size_t)N * 64 * 4);
  float* Hb = (float*)alloc((size_t)N * 64 * 4);
  int* counts  = (int*)alloc((size_t)N * 4);
  int* rowptr  = (int*)alloc((size_t)(N + 1) * 4);
  int* cursor  = (int*)alloc((size_t)N * 4);
  int* colidx  = (int*)alloc((size_t)E * 4);
  int* bsums   = (int*)alloc(1024 * 4);
  unsigned int* gmaxb = (unsigned int*)alloc((size_t)G * 64 * 4);
  float* gsum  = (float*)alloc((size_t)G * 64 * 4);
  float* gcnt  = (float*)alloc((size_t)G * 4);

  // ---- CSR build (edges grouped by dst) ----
  const int gridE = (E + 255) / 256;
  const int NB1 = (N + 1023) / 1024;
  hipMemsetAsync(counts, 0, (size_t)N * 4, stream);
  k_hist<<<gridE, 256, 0, stream>>>(edst, counts, E);
  k_scan1<<<NB1, 1024, 0, stream>>>(counts, rowptr, bsums, N);
  k_scan2<<<1, 64, 0, stream>>>(bsums, NB1);
  k_scan3<<<NB1, 1024, 0, stream>>>(rowptr, cursor, bsums, N, E);
  k_scatter<<<gridE, 256, 0, stream>>>(edst, cursor, colidx, E);

  // ---- 4 TransformerConv layers ----
  const int gridLin  = (N + LNODES - 1) / LNODES;
  const int gridAttn = (N + 3) / 4;
  for (int l = 0; l < 4; ++l) {
    const float *wq, *bq_, *wk, *bk_, *wv, *bv_, *we_, *ws_, *bs_, *wb_;
    const float* hin;
    if (l == 0) {
      hin = x;
      wq = Wq0; bq_ = bq0; wk = Wk0; bk_ = bk0; wv = Wv0; bv_ = bv0;
      we_ = We0; ws_ = Ws0; bs_ = bs0; wb_ = Wb0;
    } else {
      const int li = l - 1;
      hin = Hb;
      wq = Wq + li * 4096; bq_ = bq + li * 64;
      wk = Wk + li * 4096; bk_ = bk + li * 64;
      wv = Wv + li * 4096; bv_ = bv + li * 64;
      we_ = We + li * 1024;
      ws_ = Ws + li * 4096; bs_ = bs + li * 64;
      wb_ = Wb + li * 192;
    }
    k_lin<<<gridLin, 256, 0, stream>>>(hin, wq, bq_, wk, bk_, wv, bv_, ws_, bs_,
                                       Qb, Kb, Vb, Sb, N);
    k_attn<<<gridAttn, 256, 0, stream>>>(Qb, Kb, Vb, Sb, ea, esrc, colidx, rowptr,
                                         we_, wb_, Hb, N);
  }

  // ---- pooling ----
  hipMemsetAsync(gmaxb, 0, (size_t)G * 64 * 4, stream);
  hipMemsetAsync(gsum, 0, (size_t)G * 64 * 4, stream);
  hipMemsetAsync(gcnt, 0, (size_t)G * 4, stream);
  const int gridPool = (N + PCHUNK - 1) / PCHUNK;
  k_pool<<<gridPool, 64, 0, stream>>>(Hb, batch, gmaxb, gsum, gcnt, N);

  // ---- MLP head ----
  k_mlp<<<G, 256, 0, stream>>>(gmaxb, gsum, gcnt, Wlin, blin, Wout, bout,
                               (float*)d_out, G);
}

// Round 2
// 760.203 us; speedup vs baseline: 1.3712x; 1.3712x over previous
//
#include <hip/hip_runtime.h>
#include <math.h>

#define SCALEF 0.25f   // 1/sqrt(D=16)

// ======================= CSR build =======================
__global__ void k_hist(const int* __restrict__ dst, int* __restrict__ counts, int E) {
  int i = blockIdx.x * 256 + threadIdx.x;
  if (i < E) atomicAdd(&counts[dst[i]], 1);
}

__global__ __launch_bounds__(1024) void k_scan1(const int* __restrict__ counts,
                                                int* __restrict__ excl,
                                                int* __restrict__ bsums, int n) {
  __shared__ int sd[1024];
  int t = threadIdx.x;
  int i = blockIdx.x * 1024 + t;
  int v = (i < n) ? counts[i] : 0;
  sd[t] = v;
  __syncthreads();
  for (int off = 1; off < 1024; off <<= 1) {
    int x = (t >= off) ? sd[t - off] : 0;
    __syncthreads();
    sd[t] += x;
    __syncthreads();
  }
  if (i < n) excl[i] = sd[t] - v;
  if (t == 1023) bsums[blockIdx.x] = sd[1023];
}

__global__ void k_scan2(int* bsums, int nb) {
  if (threadIdx.x == 0 && blockIdx.x == 0) {
    int run = 0;
    for (int i = 0; i < nb; ++i) { int v = bsums[i]; bsums[i] = run; run += v; }
  }
}

__global__ __launch_bounds__(1024) void k_scan3(int* __restrict__ rowptr, int* __restrict__ cursor,
                                                const int* __restrict__ bsums, int n, int Etot) {
  int i = blockIdx.x * 1024 + threadIdx.x;
  if (i < n) { int v = rowptr[i] + bsums[blockIdx.x]; rowptr[i] = v; cursor[i] = v; }
  if (i == 0) rowptr[n] = Etot;
}

__global__ void k_scatter(const int* __restrict__ dst, int* __restrict__ cursor,
                          int* __restrict__ colidx, int E) {
  int i = blockIdx.x * 256 + threadIdx.x;
  if (i < E) { int pos = atomicAdd(&cursor[dst[i]], 1); colidx[pos] = i; }
}

// ======================= node linear: Q,K,V,Skip =======================
// 256 threads = 4 waves; wave w owns weight matrix w entirely in VGPRs
// (lane = output column, 64 VGPRs of weights). X rows are wave-uniform ->
// scalar loads. Inner loop is pure v_fmac. No LDS.
#define LB 64
__global__ __launch_bounds__(256) void k_lin(const float* __restrict__ X,
    const float* __restrict__ Wq, const float* __restrict__ bq,
    const float* __restrict__ Wk, const float* __restrict__ bk,
    const float* __restrict__ Wv, const float* __restrict__ bv,
    const float* __restrict__ Ws, const float* __restrict__ bs,
    float* __restrict__ Q, float* __restrict__ K, float* __restrict__ V, float* __restrict__ S,
    int n) {
  const int t = threadIdx.x;
  const int lane = t & 63;
  const int w = __builtin_amdgcn_readfirstlane(t >> 6);

  const float* __restrict__ Wsel = (w == 0) ? Wq : (w == 1) ? Wk : (w == 2) ? Wv : Ws;
  const float* __restrict__ bsel = (w == 0) ? bq : (w == 1) ? bk : (w == 2) ? bv : bs;
  float* __restrict__ Osel       = (w == 0) ? Q  : (w == 1) ? K  : (w == 2) ? V  : S;

  float wreg[64];
  #pragma unroll
  for (int k = 0; k < 64; ++k) wreg[k] = Wsel[k * 64 + lane];
  const float bias = bsel[lane];

  const int n0 = blockIdx.x * LB;
  for (int i = 0; i < LB; ++i) {
    const int node = n0 + i;
    if (node >= n) break;
    const float* __restrict__ xr = X + (size_t)node * 64;
    float a0 = 0.f, a1 = 0.f, a2 = 0.f, a3 = 0.f;
    #pragma unroll
    for (int k = 0; k < 16; ++k) {
      a0 += xr[4 * k + 0] * wreg[4 * k + 0];
      a1 += xr[4 * k + 1] * wreg[4 * k + 1];
      a2 += xr[4 * k + 2] * wreg[4 * k + 2];
      a3 += xr[4 * k + 3] * wreg[4 * k + 3];
    }
    Osel[(size_t)node * 64 + lane] = (a0 + a1) + (a2 + a3) + bias;
  }
}

// ======================= fused edge/attention kernel =======================
// One wave per destination node. Edge ids + src ids gathered coalesced by
// lanes up front; software-pipelined edge loop prefetches next K/V rows and
// edge attrs (uniform via readlane -> scalar loads) during current compute.
__global__ __launch_bounds__(256) void k_attn(
    const float* __restrict__ Q, const float* __restrict__ K, const float* __restrict__ V,
    const float* __restrict__ S, const float* __restrict__ EA,
    const int* __restrict__ esrc, const int* __restrict__ colidx,
    const int* __restrict__ rowptr,
    const float* __restrict__ We, const float* __restrict__ Wb,
    float* __restrict__ Hout, int n) {
  __shared__ float WeL[16][64];   // 4 KiB
  __shared__ float WbL[192];
  const int t = threadIdx.x;
  for (int i = t; i < 16 * 64; i += 256) WeL[i >> 6][i & 63] = We[i];
  for (int i = t; i < 192; i += 256) WbL[i] = Wb[i];
  __syncthreads();

  const int lane = t & 63;
  const int w = __builtin_amdgcn_readfirstlane(t >> 6);
  const int node = blockIdx.x * 4 + w;
  if (node >= n) return;

  const float qv = Q[(size_t)node * 64 + lane] * SCALEF;
  const float sk = S[(size_t)node * 64 + lane];
  const int r0 = rowptr[node], r1 = rowptr[node + 1];

  float m = -1e30f, ssum = 0.f, acc = 0.f;

  for (int c0 = r0; c0 < r1; c0 += 64) {
    const int mc = min(64, r1 - c0);
    int eidv = 0, snv = 0;
    if (lane < mc) { eidv = colidx[c0 + lane]; snv = esrc[eidv]; }

    // prefetch edge 0
    int sn_c  = __builtin_amdgcn_readlane(snv, 0);
    int eid_c = __builtin_amdgcn_readlane(eidv, 0);
    float kc = K[(size_t)sn_c * 64 + lane];
    float vc = V[(size_t)sn_c * 64 + lane];
    const float4* eap = (const float4*)(EA + (size_t)eid_c * 16);
    float4 A0 = eap[0], A1 = eap[1], A2 = eap[2], A3 = eap[3];

    for (int j = 0; j < mc; ++j) {
      float kn = 0.f, vn = 0.f;
      float4 B0, B1, B2, B3;
      B0 = B1 = B2 = B3 = make_float4(0.f, 0.f, 0.f, 0.f);
      if (j + 1 < mc) {
        const int sn1  = __builtin_amdgcn_readlane(snv, j + 1);
        const int eid1 = __builtin_amdgcn_readlane(eidv, j + 1);
        kn = K[(size_t)sn1 * 64 + lane];
        vn = V[(size_t)sn1 * 64 + lane];
        const float4* ebp = (const float4*)(EA + (size_t)eid1 * 16);
        B0 = ebp[0]; B1 = ebp[1]; B2 = ebp[2]; B3 = ebp[3];
      }

      // e = edge_attr @ We   (row uniform across wave, in A0..A3)
      float e = A0.x * WeL[0][lane]  + A0.y * WeL[1][lane]  + A0.z * WeL[2][lane]  + A0.w * WeL[3][lane]
              + A1.x * WeL[4][lane]  + A1.y * WeL[5][lane]  + A1.z * WeL[6][lane]  + A1.w * WeL[7][lane]
              + A2.x * WeL[8][lane]  + A2.y * WeL[9][lane]  + A2.z * WeL[10][lane] + A2.w * WeL[11][lane]
              + A3.x * WeL[12][lane] + A3.y * WeL[13][lane] + A3.z * WeL[14][lane] + A3.w * WeL[15][lane];
      const float ke = kc + e;
      const float ve = vc + e;
      float prod = qv * ke;
      #pragma unroll
      for (int off = 1; off < 16; off <<= 1) prod += __shfl_xor(prod, off, 64);
      const float l = prod;
      const float mn = fmaxf(m, l);
      const float fold = __expf(m - mn);
      const float p = __expf(l - mn);
      ssum = ssum * fold + p;
      acc  = acc  * fold + p * ve;
      m = mn;

      kc = kn; vc = vn; A0 = B0; A1 = B1; A2 = B2; A3 = B3;
    }
  }

  const float a = acc / (ssum + 1e-16f);
  float contrib = a * WbL[lane] + sk * WbL[64 + lane] + (a - sk) * WbL[128 + lane];
  #pragma unroll
  for (int off = 1; off < 64; off <<= 1) contrib += __shfl_xor(contrib, off, 64);
  const float beta = 1.f / (1.f + __expf(-contrib));
  const float o = beta * sk + (1.f - beta) * a;
  Hout[(size_t)node * 64 + lane] = fmaxf(o, 0.f);
}

// ======================= pooling: one block per graph, batch sorted =======================
__global__ __launch_bounds__(256) void k_pool(const float* __restrict__ Hf,
    const int* __restrict__ batch,
    float* __restrict__ gmax, float* __restrict__ gmean, int n) {
  const int g = blockIdx.x;
  const int lane = threadIdx.x & 63;
  const int w = threadIdx.x >> 6;

  // binary search bounds of graph g in sorted batch
  int a = 0, b = n;
  while (a < b) { int mid = (a + b) >> 1; if (batch[mid] < g) a = mid + 1; else b = mid; }
  const int lo = a;
  b = n;
  while (a < b) { int mid = (a + b) >> 1; if (batch[mid] < g + 1) a = mid + 1; else b = mid; }
  const int hi = a;

  float vmax = -1e30f, vsum = 0.f;
  for (int i = lo + w; i < hi; i += 4) {
    const float v = Hf[(size_t)i * 64 + lane];
    vmax = fmaxf(vmax, v);
    vsum += v;
  }
  __shared__ float smax[4][64], ssum[4][64];
  smax[w][lane] = vmax;
  ssum[w][lane] = vsum;
  __syncthreads();
  if (w == 0) {
    const float mx = fmaxf(fmaxf(smax[0][lane], smax[1][lane]),
                           fmaxf(smax[2][lane], smax[3][lane]));
    const float sm = ssum[0][lane] + ssum[1][lane] + ssum[2][lane] + ssum[3][lane];
    const int cnt = hi - lo;
    gmax[g * 64 + lane]  = (cnt > 0) ? mx : 0.f;
    gmean[g * 64 + lane] = sm / fmaxf((float)cnt, 1.f);
  }
}

// ======================= final MLP =======================
__global__ __launch_bounds__(256) void k_mlp(const float* __restrict__ gmax,
    const float* __restrict__ gmean,
    const float* __restrict__ Wlin, const float* __restrict__ blin,
    const float* __restrict__ Wout, const float* __restrict__ bout,
    float* __restrict__ out, int G) {
  __shared__ float cat[128];
  __shared__ float red[4];
  const int g = blockIdx.x;
  const int t = threadIdx.x;
  if (t < 64) cat[t] = gmax[g * 64 + t];
  else if (t < 128) cat[t] = gmean[g * 64 + (t - 64)];
  __syncthreads();
  float acc = blin[t];
  for (int j = 0; j < 128; ++j) acc += cat[j] * Wlin[j * 256 + t];
  float p = acc * Wout[t];
  #pragma unroll
  for (int off = 1; off < 64; off <<= 1) p += __shfl_xor(p, off, 64);
  if ((t & 63) == 0) red[t >> 6] = p;
  __syncthreads();
  if (t == 0) {
    const float z = red[0] + red[1] + red[2] + red[3] + bout[0];
    out[g] = 1.f / (1.f + __expf(-z));
  }
}

// ======================= launcher =======================
extern "C" void kernel_launch(void* const* d_in, const int* in_sizes, int n_in,
                              void* d_out, int out_size, void* d_ws, size_t ws_size,
                              hipStream_t stream) {
  const float* x     = (const float*)d_in[0];
  const float* ea    = (const float*)d_in[1];
  const int*   eidx  = (const int*)d_in[2];
  const int*   batch = (const int*)d_in[3];
  const float *Wq0 = (const float*)d_in[4],  *bq0 = (const float*)d_in[5];
  const float *Wk0 = (const float*)d_in[6],  *bk0 = (const float*)d_in[7];
  const float *Wv0 = (const float*)d_in[8],  *bv0 = (const float*)d_in[9];
  const float *We0 = (const float*)d_in[10];
  const float *Ws0 = (const float*)d_in[11], *bs0 = (const float*)d_in[12];
  const float *Wb0 = (const float*)d_in[13];
  const float *Wq  = (const float*)d_in[14], *bq  = (const float*)d_in[15];
  const float *Wk  = (const float*)d_in[16], *bk  = (const float*)d_in[17];
  const float *Wv  = (const float*)d_in[18], *bv  = (const float*)d_in[19];
  const float *We  = (const float*)d_in[20];
  const float *Ws  = (const float*)d_in[21], *bs  = (const float*)d_in[22];
  const float *Wb  = (const float*)d_in[23];
  const float *Wlin = (const float*)d_in[24], *blin = (const float*)d_in[25];
  const float *Wout = (const float*)d_in[26], *bout = (const float*)d_in[27];

  const int N = in_sizes[0] / 64;
  const int E = in_sizes[2] / 2;
  const int G = out_size;
  const int* esrc = eidx;
  const int* edst = eidx + E;

  // ---- workspace carve ----
  char* wsp = (char*)d_ws;
  auto alloc = [&](size_t bytes) -> void* {
    void* p = (void*)wsp;
    wsp += (bytes + 255) & ~(size_t)255;
    return p;
  };
  float* Qb = (float*)alloc((size_t)N * 64 * 4);
  float* Kb = (float*)alloc((size_t)N * 64 * 4);
  float* Vb = (float*)alloc((size_t)N * 64 * 4);
  float* Sb = (float*)alloc((size_t)N * 64 * 4);
  float* Hb = (float*)alloc((size_t)N * 64 * 4);
  int* counts  = (int*)alloc((size_t)N * 4);
  int* rowptr  = (int*)alloc((size_t)(N + 1) * 4);
  int* cursor  = (int*)alloc((size_t)N * 4);
  int* colidx  = (int*)alloc((size_t)E * 4);
  int* bsums   = (int*)alloc(1024 * 4);
  float* gmaxf  = (float*)alloc((size_t)G * 64 * 4);
  float* gmeanf = (float*)alloc((size_t)G * 64 * 4);

  // ---- CSR build (edges grouped by dst) ----
  const int gridE = (E + 255) / 256;
  const int NB1 = (N + 1023) / 1024;
  hipMemsetAsync(counts, 0, (size_t)N * 4, stream);
  k_hist<<<gridE, 256, 0, stream>>>(edst, counts, E);
  k_scan1<<<NB1, 1024, 0, stream>>>(counts, rowptr, bsums, N);
  k_scan2<<<1, 64, 0, stream>>>(bsums, NB1);
  k_scan3<<<NB1, 1024, 0, stream>>>(rowptr, cursor, bsums, N, E);
  k_scatter<<<gridE, 256, 0, stream>>>(edst, cursor, colidx, E);

  // ---- 4 TransformerConv layers ----
  const int gridLin  = (N + LB - 1) / LB;
  const int gridAttn = (N + 3) / 4;
  for (int l = 0; l < 4; ++l) {
    const float *wq, *bq_, *wk, *bk_, *wv, *bv_, *we_, *ws_, *bs_, *wb_;
    const float* hin;
    if (l == 0) {
      hin = x;
      wq = Wq0; bq_ = bq0; wk = Wk0; bk_ = bk0; wv = Wv0; bv_ = bv0;
      we_ = We0; ws_ = Ws0; bs_ = bs0; wb_ = Wb0;
    } else {
      const int li = l - 1;
      hin = Hb;
      wq = Wq + li * 4096; bq_ = bq + li * 64;
      wk = Wk + li * 4096; bk_ = bk + li * 64;
      wv = Wv + li * 4096; bv_ = bv + li * 64;
      we_ = We + li * 1024;
      ws_ = Ws + li * 4096; bs_ = bs + li * 64;
      wb_ = Wb + li * 192;
    }
    k_lin<<<gridLin, 256, 0, stream>>>(hin, wq, bq_, wk, bk_, wv, bv_, ws_, bs_,
                                       Qb, Kb, Vb, Sb, N);
    k_attn<<<gridAttn, 256, 0, stream>>>(Qb, Kb, Vb, Sb, ea, esrc, colidx, rowptr,
                                         we_, wb_, Hb, N);
  }

  // ---- pooling: one block per graph ----
  k_pool<<<G, 256, 0, stream>>>(Hb, batch, gmaxf, gmeanf, N);

  // ---- MLP head ----
  k_mlp<<<G, 256, 0, stream>>>(gmaxf, gmeanf, Wlin, blin, Wout, bout,
                               (float*)d_out, G);
}

// Round 3
// 503.603 us; speedup vs baseline: 2.0698x; 1.5095x over previous
//
#include <hip/hip_runtime.h>
#include <math.h>

#define SCALEF 0.25f   // 1/sqrt(D=16)

// ======================= CSR build =======================
__global__ void k_hist(const int* __restrict__ dst, int* __restrict__ counts, int E) {
  int i = blockIdx.x * 256 + threadIdx.x;
  if (i < E) atomicAdd(&counts[dst[i]], 1);
}

__global__ __launch_bounds__(1024) void k_scan1(const int* __restrict__ counts,
                                                int* __restrict__ excl,
                                                int* __restrict__ bsums, int n) {
  __shared__ int sd[1024];
  int t = threadIdx.x;
  int i = blockIdx.x * 1024 + t;
  int v = (i < n) ? counts[i] : 0;
  sd[t] = v;
  __syncthreads();
  for (int off = 1; off < 1024; off <<= 1) {
    int x = (t >= off) ? sd[t - off] : 0;
    __syncthreads();
    sd[t] += x;
    __syncthreads();
  }
  if (i < n) excl[i] = sd[t] - v;
  if (t == 1023) bsums[blockIdx.x] = sd[1023];
}

__global__ void k_scan2(int* bsums, int nb) {
  if (threadIdx.x == 0 && blockIdx.x == 0) {
    int run = 0;
    for (int i = 0; i < nb; ++i) { int v = bsums[i]; bsums[i] = run; run += v; }
  }
}

__global__ __launch_bounds__(1024) void k_scan3(int* __restrict__ rowptr, int* __restrict__ cursor,
                                                const int* __restrict__ bsums, int n, int Etot) {
  int i = blockIdx.x * 1024 + threadIdx.x;
  if (i < n) { int v = rowptr[i] + bsums[blockIdx.x]; rowptr[i] = v; cursor[i] = v; }
  if (i == 0) rowptr[n] = Etot;
}

__global__ void k_scatter(const int* __restrict__ dst, int* __restrict__ cursor,
                          int* __restrict__ colidx, int E) {
  int i = blockIdx.x * 256 + threadIdx.x;
  if (i < E) { int pos = atomicAdd(&cursor[dst[i]], 1); colidx[pos] = i; }
}

// ======================= node linear: Q,K,V,Skip =======================
// Register-blocked LDS GEMM. Block = 64 nodes, 4 waves. X staged TRANSPOSED
// (Xl[k][row], row-stride 68 floats: 272B = 17*16B keeps b128 alignment and
// caps bank conflicts at 2-way = free). Each lane computes a 4x4 outer-product
// tile: per k, 2x ds_read_b128 feed 16 v_fmac. W staged 2 matrices per phase.
#define LB 64
#define XPAD 68
__global__ __launch_bounds__(256) void k_lin(const float* __restrict__ X,
    const float* __restrict__ Wq, const float* __restrict__ bq,
    const float* __restrict__ Wk, const float* __restrict__ bk,
    const float* __restrict__ Wv, const float* __restrict__ bv,
    const float* __restrict__ Ws, const float* __restrict__ bs,
    float* __restrict__ Q, float* __restrict__ K, float* __restrict__ V, float* __restrict__ S,
    int n) {
  __shared__ float Xl[64][XPAD];     // 17.4 KB
  __shared__ float Wl[2][64][64];    // 32 KB
  const int t = threadIdx.x;
  const int lane = t & 63;
  const int wv = t >> 6;
  const int n0 = blockIdx.x * LB;

  // ---- stage X transposed: Xl[k][row] = X[n0+row][k] ----
  {
    const int row = t >> 2;                  // 0..63
    const int node = n0 + row;
    const bool ok = node < n;
    const float4* src = (const float4*)(X + (size_t)node * 64);
    #pragma unroll
    for (int cc = 0; cc < 4; ++cc) {
      const int chunk = (t & 3) + cc * 4;    // 0..15
      float4 v = ok ? src[chunk] : make_float4(0.f, 0.f, 0.f, 0.f);
      const int k0 = chunk * 4;
      Xl[k0 + 0][row] = v.x;
      Xl[k0 + 1][row] = v.y;
      Xl[k0 + 2][row] = v.z;
      Xl[k0 + 3][row] = v.w;
    }
  }

  const float* Wm[4] = {Wq, Wk, Wv, Ws};
  const float* bm[4] = {bq, bk, bv, bs};
  float* Om[4] = {Q, K, V, S};

  const int rg = lane >> 2;                  // row group: rows rg*4 .. rg*4+3
  const int c0 = wv * 16 + (lane & 3) * 4;   // this lane's 4 output cols

  for (int ph = 0; ph < 2; ++ph) {
    if (ph) __syncthreads();                 // prev compute done before Wl overwrite
    // stage 2 weight matrices
    {
      const float4* w0 = (const float4*)Wm[ph * 2 + 0];
      const float4* w1 = (const float4*)Wm[ph * 2 + 1];
      float4* d0 = (float4*)&Wl[0][0][0];
      float4* d1 = (float4*)&Wl[1][0][0];
      for (int i = t; i < 1024; i += 256) { d0[i] = w0[i]; d1[i] = w1[i]; }
    }
    __syncthreads();

    #pragma unroll
    for (int m = 0; m < 2; ++m) {
      const int mat = ph * 2 + m;
      float a[4][4];
      #pragma unroll
      for (int i = 0; i < 4; ++i)
        #pragma unroll
        for (int j = 0; j < 4; ++j) a[i][j] = 0.f;

      #pragma unroll 8
      for (int k = 0; k < 64; ++k) {
        const float4 xv = *(const float4*)&Xl[k][rg * 4];
        const float4 wv4 = *(const float4*)&Wl[m][k][c0];
        const float xs[4] = {xv.x, xv.y, xv.z, xv.w};
        #pragma unroll
        for (int i = 0; i < 4; ++i) {
          a[i][0] += xs[i] * wv4.x;
          a[i][1] += xs[i] * wv4.y;
          a[i][2] += xs[i] * wv4.z;
          a[i][3] += xs[i] * wv4.w;
        }
      }

      const float4 bias = *(const float4*)(bm[mat] + c0);
      float* O = Om[mat];
      #pragma unroll
      for (int i = 0; i < 4; ++i) {
        const int node = n0 + rg * 4 + i;
        if (node < n) {
          float4 r;
          r.x = a[i][0] + bias.x;
          r.y = a[i][1] + bias.y;
          r.z = a[i][2] + bias.z;
          r.w = a[i][3] + bias.w;
          *(float4*)(O + (size_t)node * 64 + c0) = r;
        }
      }
    }
  }
}

// ======================= fused edge/attention kernel =======================
// One wave per destination node. Edge ids + src ids gathered coalesced by
// lanes up front; software-pipelined edge loop prefetches next K/V rows and
// edge attrs (uniform via readlane -> scalar loads) during current compute.
__global__ __launch_bounds__(256) void k_attn(
    const float* __restrict__ Q, const float* __restrict__ K, const float* __restrict__ V,
    const float* __restrict__ S, const float* __restrict__ EA,
    const int* __restrict__ esrc, const int* __restrict__ colidx,
    const int* __restrict__ rowptr,
    const float* __restrict__ We, const float* __restrict__ Wb,
    float* __restrict__ Hout, int n) {
  __shared__ float WeL[16][64];   // 4 KiB
  __shared__ float WbL[192];
  const int t = threadIdx.x;
  for (int i = t; i < 16 * 64; i += 256) WeL[i >> 6][i & 63] = We[i];
  for (int i = t; i < 192; i += 256) WbL[i] = Wb[i];
  __syncthreads();

  const int lane = t & 63;
  const int w = __builtin_amdgcn_readfirstlane(t >> 6);
  const int node = blockIdx.x * 4 + w;
  if (node >= n) return;

  const float qv = Q[(size_t)node * 64 + lane] * SCALEF;
  const float sk = S[(size_t)node * 64 + lane];
  const int r0 = rowptr[node], r1 = rowptr[node + 1];

  float m = -1e30f, ssum = 0.f, acc = 0.f;

  for (int c0 = r0; c0 < r1; c0 += 64) {
    const int mc = min(64, r1 - c0);
    int eidv = 0, snv = 0;
    if (lane < mc) { eidv = colidx[c0 + lane]; snv = esrc[eidv]; }

    // prefetch edge 0
    int sn_c  = __builtin_amdgcn_readlane(snv, 0);
    int eid_c = __builtin_amdgcn_readlane(eidv, 0);
    float kc = K[(size_t)sn_c * 64 + lane];
    float vc = V[(size_t)sn_c * 64 + lane];
    const float4* eap = (const float4*)(EA + (size_t)eid_c * 16);
    float4 A0 = eap[0], A1 = eap[1], A2 = eap[2], A3 = eap[3];

    for (int j = 0; j < mc; ++j) {
      float kn = 0.f, vn = 0.f;
      float4 B0, B1, B2, B3;
      B0 = B1 = B2 = B3 = make_float4(0.f, 0.f, 0.f, 0.f);
      if (j + 1 < mc) {
        const int sn1  = __builtin_amdgcn_readlane(snv, j + 1);
        const int eid1 = __builtin_amdgcn_readlane(eidv, j + 1);
        kn = K[(size_t)sn1 * 64 + lane];
        vn = V[(size_t)sn1 * 64 + lane];
        const float4* ebp = (const float4*)(EA + (size_t)eid1 * 16);
        B0 = ebp[0]; B1 = ebp[1]; B2 = ebp[2]; B3 = ebp[3];
      }

      // e = edge_attr @ We   (row uniform across wave, in A0..A3)
      float e = A0.x * WeL[0][lane]  + A0.y * WeL[1][lane]  + A0.z * WeL[2][lane]  + A0.w * WeL[3][lane]
              + A1.x * WeL[4][lane]  + A1.y * WeL[5][lane]  + A1.z * WeL[6][lane]  + A1.w * WeL[7][lane]
              + A2.x * WeL[8][lane]  + A2.y * WeL[9][lane]  + A2.z * WeL[10][lane] + A2.w * WeL[11][lane]
              + A3.x * WeL[12][lane] + A3.y * WeL[13][lane] + A3.z * WeL[14][lane] + A3.w * WeL[15][lane];
      const float ke = kc + e;
      const float ve = vc + e;
      float prod = qv * ke;
      #pragma unroll
      for (int off = 1; off < 16; off <<= 1) prod += __shfl_xor(prod, off, 64);
      const float l = prod;
      const float mn = fmaxf(m, l);
      const float fold = __expf(m - mn);
      const float p = __expf(l - mn);
      ssum = ssum * fold + p;
      acc  = acc  * fold + p * ve;
      m = mn;

      kc = kn; vc = vn; A0 = B0; A1 = B1; A2 = B2; A3 = B3;
    }
  }

  const float a = acc / (ssum + 1e-16f);
  float contrib = a * WbL[lane] + sk * WbL[64 + lane] + (a - sk) * WbL[128 + lane];
  #pragma unroll
  for (int off = 1; off < 64; off <<= 1) contrib += __shfl_xor(contrib, off, 64);
  const float beta = 1.f / (1.f + __expf(-contrib));
  const float o = beta * sk + (1.f - beta) * a;
  Hout[(size_t)node * 64 + lane] = fmaxf(o, 0.f);
}

// ======================= pooling: one block per graph, batch sorted =======================
__global__ __launch_bounds__(256) void k_pool(const float* __restrict__ Hf,
    const int* __restrict__ batch,
    float* __restrict__ gmax, float* __restrict__ gmean, int n) {
  const int g = blockIdx.x;
  const int lane = threadIdx.x & 63;
  const int w = threadIdx.x >> 6;

  // binary search bounds of graph g in sorted batch
  int a = 0, b = n;
  while (a < b) { int mid = (a + b) >> 1; if (batch[mid] < g) a = mid + 1; else b = mid; }
  const int lo = a;
  b = n;
  while (a < b) { int mid = (a + b) >> 1; if (batch[mid] < g + 1) a = mid + 1; else b = mid; }
  const int hi = a;

  float vmax = -1e30f, vsum = 0.f;
  for (int i = lo + w; i < hi; i += 4) {
    const float v = Hf[(size_t)i * 64 + lane];
    vmax = fmaxf(vmax, v);
    vsum += v;
  }
  __shared__ float smax[4][64], ssum[4][64];
  smax[w][lane] = vmax;
  ssum[w][lane] = vsum;
  __syncthreads();
  if (w == 0) {
    const float mx = fmaxf(fmaxf(smax[0][lane], smax[1][lane]),
                           fmaxf(smax[2][lane], smax[3][lane]));
    const float sm = ssum[0][lane] + ssum[1][lane] + ssum[2][lane] + ssum[3][lane];
    const int cnt = hi - lo;
    gmax[g * 64 + lane]  = (cnt > 0) ? mx : 0.f;
    gmean[g * 64 + lane] = sm / fmaxf((float)cnt, 1.f);
  }
}

// ======================= final MLP =======================
__global__ __launch_bounds__(256) void k_mlp(const float* __restrict__ gmax,
    const float* __restrict__ gmean,
    const float* __restrict__ Wlin, const float* __restrict__ blin,
    const float* __restrict__ Wout, const float* __restrict__ bout,
    float* __restrict__ out, int G) {
  __shared__ float cat[128];
  __shared__ float red[4];
  const int g = blockIdx.x;
  const int t = threadIdx.x;
  if (t < 64) cat[t] = gmax[g * 64 + t];
  else if (t < 128) cat[t] = gmean[g * 64 + (t - 64)];
  __syncthreads();
  float acc = blin[t];
  for (int j = 0; j < 128; ++j) acc += cat[j] * Wlin[j * 256 + t];
  float p = acc * Wout[t];
  #pragma unroll
  for (int off = 1; off < 64; off <<= 1) p += __shfl_xor(p, off, 64);
  if ((t & 63) == 0) red[t >> 6] = p;
  __syncthreads();
  if (t == 0) {
    const float z = red[0] + red[1] + red[2] + red[3] + bout[0];
    out[g] = 1.f / (1.f + __expf(-z));
  }
}

// ======================= launcher =======================
extern "C" void kernel_launch(void* const* d_in, const int* in_sizes, int n_in,
                              void* d_out, int out_size, void* d_ws, size_t ws_size,
                              hipStream_t stream) {
  const float* x     = (const float*)d_in[0];
  const float* ea    = (const float*)d_in[1];
  const int*   eidx  = (const int*)d_in[2];
  const int*   batch = (const int*)d_in[3];
  const float *Wq0 = (const float*)d_in[4],  *bq0 = (const float*)d_in[5];
  const float *Wk0 = (const float*)d_in[6],  *bk0 = (const float*)d_in[7];
  const float *Wv0 = (const float*)d_in[8],  *bv0 = (const float*)d_in[9];
  const float *We0 = (const float*)d_in[10];
  const float *Ws0 = (const float*)d_in[11], *bs0 = (const float*)d_in[12];
  const float *Wb0 = (const float*)d_in[13];
  const float *Wq  = (const float*)d_in[14], *bq  = (const float*)d_in[15];
  const float *Wk  = (const float*)d_in[16], *bk  = (const float*)d_in[17];
  const float *Wv  = (const float*)d_in[18], *bv  = (const float*)d_in[19];
  const float *We  = (const float*)d_in[20];
  const float *Ws  = (const float*)d_in[21], *bs  = (const float*)d_in[22];
  const float *Wb  = (const float*)d_in[23];
  const float *Wlin = (const float*)d_in[24], *blin = (const float*)d_in[25];
  const float *Wout = (const float*)d_in[26], *bout = (const float*)d_in[27];

  const int N = in_sizes[0] / 64;
  const int E = in_sizes[2] / 2;
  const int G = out_size;
  const int* esrc = eidx;
  const int* edst = eidx + E;

  // ---- workspace carve ----
  char* wsp = (char*)d_ws;
  auto alloc = [&](size_t bytes) -> void* {
    void* p = (void*)wsp;
    wsp += (bytes + 255) & ~(size_t)255;
    return p;
  };
  float* Qb = (float*)alloc((size_t)N * 64 * 4);
  float* Kb = (float*)alloc((size_t)N * 64 * 4);
  float* Vb = (float*)alloc((size_t)N * 64 * 4);
  float* Sb = (float*)alloc((size_t)N * 64 * 4);
  float* Hb = (float*)alloc((size_t)N * 64 * 4);
  int* counts  = (int*)alloc((size_t)N * 4);
  int* rowptr  = (int*)alloc((size_t)(N + 1) * 4);
  int* cursor  = (int*)alloc((size_t)N * 4);
  int* colidx  = (int*)alloc((size_t)E * 4);
  int* bsums   = (int*)alloc(1024 * 4);
  float* gmaxf  = (float*)alloc((size_t)G * 64 * 4);
  float* gmeanf = (float*)alloc((size_t)G * 64 * 4);

  // ---- CSR build (edges grouped by dst) ----
  const int gridE = (E + 255) / 256;
  const int NB1 = (N + 1023) / 1024;
  hipMemsetAsync(counts, 0, (size_t)N * 4, stream);
  k_hist<<<gridE, 256, 0, stream>>>(edst, counts, E);
  k_scan1<<<NB1, 1024, 0, stream>>>(counts, rowptr, bsums, N);
  k_scan2<<<1, 64, 0, stream>>>(bsums, NB1);
  k_scan3<<<NB1, 1024, 0, stream>>>(rowptr, cursor, bsums, N, E);
  k_scatter<<<gridE, 256, 0, stream>>>(edst, cursor, colidx, E);

  // ---- 4 TransformerConv layers ----
  const int gridLin  = (N + LB - 1) / LB;
  const int gridAttn = (N + 3) / 4;
  for (int l = 0; l < 4; ++l) {
    const float *wq, *bq_, *wk, *bk_, *wv, *bv_, *we_, *ws_, *bs_, *wb_;
    const float* hin;
    if (l == 0) {
      hin = x;
      wq = Wq0; bq_ = bq0; wk = Wk0; bk_ = bk0; wv = Wv0; bv_ = bv0;
      we_ = We0; ws_ = Ws0; bs_ = bs0; wb_ = Wb0;
    } else {
      const int li = l - 1;
      hin = Hb;
      wq = Wq + li * 4096; bq_ = bq + li * 64;
      wk = Wk + li * 4096; bk_ = bk + li * 64;
      wv = Wv + li * 4096; bv_ = bv + li * 64;
      we_ = We + li * 1024;
      ws_ = Ws + li * 4096; bs_ = bs + li * 64;
      wb_ = Wb + li * 192;
    }
    k_lin<<<gridLin, 256, 0, stream>>>(hin, wq, bq_, wk, bk_, wv, bv_, ws_, bs_,
                                       Qb, Kb, Vb, Sb, N);
    k_attn<<<gridAttn, 256, 0, stream>>>(Qb, Kb, Vb, Sb, ea, esrc, colidx, rowptr,
                                         we_, wb_, Hb, N);
  }

  // ---- pooling: one block per graph ----
  k_pool<<<G, 256, 0, stream>>>(Hb, batch, gmaxf, gmeanf, N);

  // ---- MLP head ----
  k_mlp<<<G, 256, 0, stream>>>(gmaxf, gmeanf, Wlin, blin, Wout, bout,
                               (float*)d_out, G);
}